// Round 2
// baseline (2576.245 us; speedup 1.0000x reference)
//
#include <hip/hip_runtime.h>

#define KP 32   // particles
#define BN 256  // batch
#define TN 32   // time steps
#define DHN 128 // hidden
#define ROWS (KP*BN) // 8192

// ---------------- init: zero h/c state, identity resample indices ----------------
__global__ void k_init(float* __restrict__ hc0, int* __restrict__ hsrc, int* __restrict__ csrc) {
    int i = blockIdx.x * 256 + threadIdx.x;
    if (i < 2097152) hc0[i] = 0.f;
    if (i < ROWS) { hsrc[i] = i >> 8; csrc[i] = i >> 8; }
}

// ---------------- precompute enc @ W1[256:384] ----------------
__global__ void k_encproj(const float* __restrict__ enc, const float* __restrict__ W1,
                          float* __restrict__ encp) {
    int bt = blockIdx.x;           // [0, B*T)
    int e  = threadIdx.x;          // 128
    __shared__ float row[128];
    row[e] = enc[bt * 128 + e];
    __syncthreads();
    float acc = 0.f;
#pragma unroll 8
    for (int c = 0; c < 128; ++c)
        acc = fmaf(row[c], W1[(256 + c) * 128 + e], acc);
    encp[bt * 128 + e] = acc;
}

// ---------------- fused: gathered means -> attention -> context -> y_tilde -> var ----------------
// one block per batch b, 256 threads
__global__ __launch_bounds__(256)
void k_attn(const float* __restrict__ h, const float* __restrict__ c,
            const int* __restrict__ hsrc, const int* __restrict__ csrc,
            const float* __restrict__ encp, const float* __restrict__ enc,
            const float* __restrict__ W1, const float* __restrict__ b1,
            const float* __restrict__ W2, const float* __restrict__ b2v,
            const float* __restrict__ fcW, const float* __restrict__ fcb,
            const float* __restrict__ varW, const float* __restrict__ varb,
            const float* __restrict__ yprev,
            float* __restrict__ ctxg, float* __restrict__ ytg, float* __restrict__ vspg,
            int t) {
    int b = blockIdx.x, tid = threadIdx.x;
    __shared__ float hb[128], cb[128], hcp[128], aa[32], beta[32], red[128];
    __shared__ int hsl[32], csl[32];
    __shared__ float yts;

    if (tid < 32) hsl[tid] = hsrc[tid * BN + b];
    else if (tid < 64) csl[tid - 32] = csrc[(tid - 32) * BN + b];
    __syncthreads();

    // phase 1: particle means (through resample indirection)
    if (tid < 128) {
        float s = 0.f;
#pragma unroll 4
        for (int k = 0; k < KP; ++k)
            s += h[((size_t)hsl[k] * BN + b) * 128 + tid];
        hb[tid] = s * (1.f / 32.f);
    } else {
        int d = tid - 128;
        float s = 0.f;
#pragma unroll 4
        for (int k = 0; k < KP; ++k)
            s += c[((size_t)csl[k] * BN + b) * 128 + d];
        cb[d] = s * (1.f / 32.f);
    }
    __syncthreads();

    // phase 2: hc_proj[e] = hbar@W1[0:128] + cbar@W1[128:256] + b1
    {
        int e = tid & 127, half = tid >> 7;
        const float* Wb  = W1 + half * 128 * 128;
        const float* hcl = half ? cb : hb;
        float acc = 0.f;
#pragma unroll 8
        for (int d = 0; d < 128; ++d)
            acc = fmaf(hcl[d], Wb[d * 128 + e], acc);
        if (half) red[e] = acc;
        __syncthreads();
        if (!half) hcp[e] = acc + red[e] + b1[e];
    }
    __syncthreads();

    // phase 3: scores a[tq] = sum_e tanh(hcp[e]+encp[b,tq,e]) * W2[e] + b2
    {
        int w = tid >> 6, lane = tid & 63;
        for (int tt = 0; tt < 8; ++tt) {
            int tq = w * 8 + tt;
            float v = 0.f;
#pragma unroll
            for (int hh = 0; hh < 2; ++hh) {
                int e = lane + 64 * hh;
                v += tanhf(hcp[e] + encp[(b * TN + tq) * 128 + e]) * W2[e];
            }
#pragma unroll
            for (int off = 32; off; off >>= 1) v += __shfl_xor(v, off, 64);
            if (lane == 0) aa[tq] = v + b2v[0];
        }
    }
    __syncthreads();

    // phase 4: softmax over T (max-subtracted, like jax.nn.softmax)
    if (tid < 32) {
        float m = -1e30f;
        for (int i = 0; i < 32; ++i) m = fmaxf(m, aa[i]);
        float s = 0.f;
        for (int i = 0; i < 32; ++i) s += expf(aa[i] - m);
        beta[tid] = expf(aa[tid] - m) / s;
    }
    __syncthreads();

    // context + y_tilde
    if (tid < 128) {
        float acc = 0.f;
#pragma unroll 4
        for (int tq = 0; tq < 32; ++tq)
            acc = fmaf(beta[tq], enc[(b * TN + tq) * 128 + tid], acc);
        ctxg[b * 128 + tid] = acc;
        red[tid] = acc * fcW[tid];
    }
    __syncthreads();
    if (tid < 64) red[tid] += red[tid + 64];
    __syncthreads();
    if (tid < 64) {
        float v = red[tid];
#pragma unroll
        for (int off = 32; off; off >>= 1) v += __shfl_xor(v, off, 64);
        if (tid == 0) {
            float yv = v + yprev[b * TN + t] * fcW[128] + fcb[0];
            yts = yv;
            ytg[b] = yv;
        }
    }
    __syncthreads();

    // phase 6: var[j] = yt*varW[0,j] + hbar@varW[1:,j] + varb; softplus
    if (tid < 128) {
        int j = tid;
        float v = fmaf(yts, varW[j], varb[j]);
#pragma unroll 8
        for (int d = 0; d < 128; ++d)
            v = fmaf(hb[d], varW[(1 + d) * 128 + j], v);
        float sp = fmaxf(v, 0.f) + log1pf(expf(-fabsf(v)));
        vspg[b * 128 + j] = sp;
    }
}

// ---------------- LSTM step (gathered inputs) + reparam + fused proj/pdf dots ----------------
// block: 256 thr = 64 lanes (c0) x 4 row-groups (8 rows each) => 32 rows/block, grid 256
__global__ __launch_bounds__(256)
void k_lstm(const float* __restrict__ h, const float* __restrict__ c,
            const int* __restrict__ hsrc, const int* __restrict__ csrc,
            const float* __restrict__ Whh, const float* __restrict__ Wih,
            const float* __restrict__ bih, const float* __restrict__ bhh,
            const float* __restrict__ yt, const float* __restrict__ vsp,
            const float* __restrict__ eps,
            const float* __restrict__ fdW, const float* __restrict__ pdW,
            float* __restrict__ h2, float* __restrict__ c2,
            float* __restrict__ proj, float* __restrict__ qv, int t) {
    __shared__ float hT[32 * 128];   // 16 KB
    __shared__ float wT[16 * 512];   // 32 KB
    __shared__ int hsl[32], csl[32];
    int tid  = threadIdx.x;
    int row0 = blockIdx.x * 32;      // = k0*BN + b0, b0 multiple of 32
    int g = tid >> 6, c0 = tid & 63;

    if (tid < 32) hsl[tid] = hsrc[row0 + tid];
    else if (tid < 64) csl[tid - 32] = csrc[row0 + tid - 32];
    __syncthreads();

    // stage gathered h tile (32 rows x 128)
    {
        int b0 = row0 & 255;
#pragma unroll
        for (int it = 0; it < 4; ++it) {
            int f4 = tid + 256 * it;
            int lr = f4 >> 5, off = f4 & 31;
            ((float4*)hT)[f4] =
                ((const float4*)h)[((size_t)hsl[lr] * BN + b0 + lr) * 32 + off];
        }
    }

    float acc[8][8];
#pragma unroll
    for (int r = 0; r < 8; ++r) {
        int row = row0 + g * 8 + r;
        int bb  = row & 255;
        float ytv = yt[bb];
#pragma unroll
        for (int m = 0; m < 8; ++m) {
            int col = c0 + 64 * m;
            acc[r][m] = fmaf(ytv, Wih[col], bih[col] + bhh[col]);
        }
    }

    for (int dc = 0; dc < 8; ++dc) {
        __syncthreads();
        const float4* wsrc = (const float4*)(Whh + dc * 16 * 512);
#pragma unroll
        for (int i = 0; i < 8; ++i)
            ((float4*)wT)[tid + 256 * i] = wsrc[tid + 256 * i];
        __syncthreads();
#pragma unroll
        for (int dd = 0; dd < 16; ++dd) {
            int dglob = dc * 16 + dd;
            float wv[8];
#pragma unroll
            for (int m = 0; m < 8; ++m) wv[m] = wT[dd * 512 + c0 + 64 * m];
#pragma unroll
            for (int r = 0; r < 8; ++r) {
                float hv = hT[(g * 8 + r) * 128 + dglob];
#pragma unroll
                for (int m = 0; m < 8; ++m) acc[r][m] = fmaf(hv, wv[m], acc[r][m]);
            }
        }
    }

    // epilogue: gates for d0 = c0, c0+64; reparam; fused proj/pdf dots
#pragma unroll
    for (int r = 0; r < 8; ++r) {
        int lr  = g * 8 + r;
        int row = row0 + lr;
        int bb  = row & 255;
        float p = 0.f, q = 0.f;
#pragma unroll
        for (int mm = 0; mm < 2; ++mm) {
            int d0 = c0 + 64 * mm;
            float gi = acc[r][0 + mm], gf = acc[r][2 + mm];
            float gg = acc[r][4 + mm], go = acc[r][6 + mm];
            float si = 1.f / (1.f + expf(-gi));
            float sf = 1.f / (1.f + expf(-gf));
            float so = 1.f / (1.f + expf(-go));
            float tg = tanhf(gg);
            float cold = c[((size_t)csl[lr] * BN + bb) * 128 + d0];
            float cn = sf * cold + si * tg;
            float hn = so * tanhf(cn);
            hn = fmaf(eps[((size_t)t * ROWS + row) * 128 + d0], vsp[bb * 128 + d0], hn);
            c2[(size_t)row * 128 + d0] = cn;
            h2[(size_t)row * 128 + d0] = hn;
            p = fmaf(hn, fdW[d0], p);
            q = fmaf(hn, pdW[d0], q);
        }
#pragma unroll
        for (int off = 32; off; off >>= 1) {
            p += __shfl_xor(p, off, 64);
            q += __shfl_xor(q, off, 64);
        }
        if (c0 == 0) { proj[row] = p; qv[row] = q; }
    }
}

// ---------------- fused sort + weights (torch view(-1,K) bug) + resample ----------------
// one block per 32-batch chunk m; 1024 threads = 32 b_loc x 32 j
__global__ __launch_bounds__(1024)
void k_resample(const float* __restrict__ proj, const float* __restrict__ qv,
                const float* __restrict__ ytg, const float* __restrict__ pdW,
                const float* __restrict__ pdb, const float* __restrict__ gum,
                int* __restrict__ hsrc, int* __restrict__ csrc, int t) {
    __shared__ float pr[32][33];
    __shared__ int   ord[32][32];
    __shared__ float eps_s[32][33];  // [sorted s][b_loc]
    __shared__ float Sv[32];
    __shared__ float lw[32][33];     // [b_loc][sorted s]
    int tid = threadIdx.x;
    int bl = tid >> 5, j = tid & 31;
    int b = blockIdx.x * 32 + bl;

    pr[bl][j] = proj[j * BN + b];
    __syncthreads();

    // stable ascending argsort via rank
    {
        float pj = pr[bl][j];
        int r = 0;
#pragma unroll 8
        for (int l = 0; l < 32; ++l) {
            float pl = pr[bl][l];
            r += (pl < pj) || (pl == pj && l < j);
        }
        ord[bl][r] = j;
    }
    __syncthreads();

    // logpdf of sorted particle s=j ; exp
    {
        int jo = ord[bl][j];
        float lp = qv[jo * BN + b] + ytg[b] * pdW[128] + pdb[0];
        eps_s[j][bl] = expf(lp);
    }
    __syncthreads();

    // chunk sums S[s] (the replicated view(-1,K) normalization groups)
    if (tid < 32) {
        float s = 0.f;
#pragma unroll 8
        for (int l = 0; l < 32; ++l) s += eps_s[tid][l];
        Sv[tid] = s;
    }
    __syncthreads();

    lw[bl][j] = logf(eps_s[j][bl] / Sv[j] + 1e-30f);
    __syncthreads();

    // gumbel-max resample: knew = j ; first-occurrence argmax
    {
        const float* gb = gum + (((size_t)t * BN + b) * KP + j) * KP;
        float best = -1e38f;
        int bi = 0;
#pragma unroll 8
        for (int l = 0; l < 32; ++l) {
            float v = lw[bl][l] + gb[l];
            if (v > best) { best = v; bi = l; }
        }
        hsrc[j * BN + b] = ord[bl][bi];  // h2 sorted-gather composed -> original index
        csrc[j * BN + b] = bi;           // unsorted c2 gathered with sorted-space idx (ref bug)
    }
}

// ---------------- final outputs ----------------
__global__ void k_final(const float* __restrict__ h, const int* __restrict__ hsrc,
                        const float* __restrict__ ctx,
                        const float* __restrict__ fdW, const float* __restrict__ fdb,
                        const float* __restrict__ feW, const float* __restrict__ feb,
                        float* __restrict__ out) {
    int wid  = (blockIdx.x * 256 + threadIdx.x) >> 6;  // b
    int lane = threadIdx.x & 63;
    if (wid >= BN) return;
    float acc = 0.f;
#pragma unroll
    for (int hh = 0; hh < 2; ++hh) {
        int d = lane + 64 * hh;
        float s = 0.f;
#pragma unroll 4
        for (int k = 0; k < KP; ++k) {
            int hs = hsrc[k * BN + wid];
            s += h[((size_t)hs * BN + wid) * 128 + d];
        }
        acc = fmaf(s * (1.f / 32.f), fdW[d], acc);
        acc = fmaf(ctx[wid * 128 + d], feW[d], acc);
    }
#pragma unroll
    for (int off = 32; off; off >>= 1) acc += __shfl_xor(acc, off, 64);
    if (lane == 0) out[wid] = acc + fdb[0] + feb[0];
}

extern "C" void kernel_launch(void* const* d_in, const int* in_sizes, int n_in,
                              void* d_out, int out_size, void* d_ws, size_t ws_size,
                              hipStream_t stream) {
    const float* enc   = (const float*)d_in[0];
    const float* yprev = (const float*)d_in[1];
    const float* eps   = (const float*)d_in[2];
    const float* gum   = (const float*)d_in[3];
    const float* aW1   = (const float*)d_in[4];
    const float* ab1   = (const float*)d_in[5];
    const float* aW2   = (const float*)d_in[6];
    const float* ab2   = (const float*)d_in[7];
    const float* Wih   = (const float*)d_in[8];
    const float* Whh   = (const float*)d_in[9];
    const float* bih   = (const float*)d_in[10];
    const float* bhh   = (const float*)d_in[11];
    const float* fcW   = (const float*)d_in[12];
    const float* fcb   = (const float*)d_in[13];
    const float* fdW   = (const float*)d_in[14];
    const float* fdb   = (const float*)d_in[15];
    const float* feW   = (const float*)d_in[16];
    const float* feb   = (const float*)d_in[17];
    const float* varW  = (const float*)d_in[18];
    const float* varb  = (const float*)d_in[19];
    const float* pdW   = (const float*)d_in[20];
    const float* pdb   = (const float*)d_in[21];
    float* out = (float*)d_out;

    float* ws   = (float*)d_ws;
    float* encp = ws;                        // 1,048,576
    float* h2A  = ws + 1048576;              // 1,048,576 (h2A,c2A contiguous for zero-init)
    float* c2A  = ws + 2097152;
    float* h2B  = ws + 3145728;
    float* c2B  = ws + 4194304;
    float* ctx  = ws + 5242880;              // 32,768
    float* ytg  = ws + 5275648;              // 256
    float* vsp  = ws + 5275904;              // 32,768
    float* proj = ws + 5308672;              // 8,192
    float* qv   = ws + 5316864;              // 8,192
    int*   hsrc = (int*)(ws + 5325056);      // 8,192
    int*   csrc = (int*)(ws + 5333248);      // 8,192

    k_init<<<(2097152 + 255) / 256, 256, 0, stream>>>(h2A, hsrc, csrc);
    k_encproj<<<BN * TN, 128, 0, stream>>>(enc, aW1, encp);

    float* hc = h2A; float* cc = c2A; float* hn = h2B; float* cn = c2B;
    for (int t = 0; t < TN; ++t) {
        k_attn<<<BN, 256, 0, stream>>>(hc, cc, hsrc, csrc, encp, enc, aW1, ab1, aW2, ab2,
                                       fcW, fcb, varW, varb, yprev, ctx, ytg, vsp, t);
        k_lstm<<<ROWS / 32, 256, 0, stream>>>(hc, cc, hsrc, csrc, Whh, Wih, bih, bhh,
                                              ytg, vsp, eps, fdW, pdW, hn, cn, proj, qv, t);
        k_resample<<<BN / 32, 1024, 0, stream>>>(proj, qv, ytg, pdW, pdb, gum,
                                                 hsrc, csrc, t);
        float* th = hc; hc = hn; hn = th;
        float* tc = cc; cc = cn; cn = tc;
    }
    k_final<<<64, 256, 0, stream>>>(hc, hsrc, ctx, fdW, fdb, feW, feb, out);
}

// Round 3
// 2362.766 us; speedup vs baseline: 1.0904x; 1.0904x over previous
//
#include <hip/hip_runtime.h>

#define KP 32   // particles
#define BN 256  // batch
#define TN 32   // time steps
#define DHN 128 // hidden
#define ROWS (KP*BN) // 8192

// ---------------- init: zero h/c state, identity resample indices ----------------
__global__ void k_init(float* __restrict__ hc0, int* __restrict__ hsrc, int* __restrict__ csrc) {
    int i = blockIdx.x * 256 + threadIdx.x;
    if (i < 2097152) hc0[i] = 0.f;
    if (i < ROWS) { hsrc[i] = i >> 8; csrc[i] = i >> 8; }
}

// ---------------- precompute enc @ W1[256:384] ----------------
__global__ void k_encproj(const float* __restrict__ enc, const float* __restrict__ W1,
                          float* __restrict__ encp) {
    int bt = blockIdx.x;           // [0, B*T)
    int e  = threadIdx.x;          // 128
    __shared__ float row[128];
    row[e] = enc[bt * 128 + e];
    __syncthreads();
    float acc = 0.f;
#pragma unroll 8
    for (int c = 0; c < 128; ++c)
        acc = fmaf(row[c], W1[(256 + c) * 128 + e], acc);
    encp[bt * 128 + e] = acc;
}

// ---------------- precompute Whh reorg: Wre[dd][d0][gate] + wih/b combos ----------------
__global__ void k_wre(const float* __restrict__ Whh, const float* __restrict__ Wih,
                      const float* __restrict__ bih, const float* __restrict__ bhh,
                      float* __restrict__ Wre, float* __restrict__ wihre,
                      float* __restrict__ bre) {
    int i = blockIdx.x * 256 + threadIdx.x;   // 0..16383
    int dd = i >> 7, d0 = i & 127;
    float4 v;
    v.x = Whh[dd * 512 + 0 * 128 + d0];
    v.y = Whh[dd * 512 + 1 * 128 + d0];
    v.z = Whh[dd * 512 + 2 * 128 + d0];
    v.w = Whh[dd * 512 + 3 * 128 + d0];
    ((float4*)Wre)[i] = v;
    if (i < 128) {
        float4 a;
        a.x = Wih[0 * 128 + d0]; a.y = Wih[1 * 128 + d0];
        a.z = Wih[2 * 128 + d0]; a.w = Wih[3 * 128 + d0];
        ((float4*)wihre)[d0] = a;
        float4 b;
        b.x = bih[0 * 128 + d0] + bhh[0 * 128 + d0];
        b.y = bih[1 * 128 + d0] + bhh[1 * 128 + d0];
        b.z = bih[2 * 128 + d0] + bhh[2 * 128 + d0];
        b.w = bih[3 * 128 + d0] + bhh[3 * 128 + d0];
        ((float4*)bre)[d0] = b;
    }
}

// ---------------- fused: gathered means -> attention -> context -> y_tilde -> var ----------------
// one block per batch b, 256 threads
__global__ __launch_bounds__(256)
void k_attn(const float* __restrict__ h, const float* __restrict__ c,
            const int* __restrict__ hsrc, const int* __restrict__ csrc,
            const float* __restrict__ encp, const float* __restrict__ enc,
            const float* __restrict__ W1, const float* __restrict__ b1,
            const float* __restrict__ W2, const float* __restrict__ b2v,
            const float* __restrict__ fcW, const float* __restrict__ fcb,
            const float* __restrict__ varW, const float* __restrict__ varb,
            const float* __restrict__ yprev,
            float* __restrict__ ctxg, float* __restrict__ ytg, float* __restrict__ vspg,
            int t) {
    int b = blockIdx.x, tid = threadIdx.x;
    __shared__ float hb[128], cb[128], hcp[128], aa[32], beta[32], red[128];
    __shared__ int hsl[32], csl[32];
    __shared__ float yts;

    if (tid < 32) hsl[tid] = hsrc[tid * BN + b];
    else if (tid < 64) csl[tid - 32] = csrc[(tid - 32) * BN + b];
    __syncthreads();

    // phase 1: particle means (through resample indirection)
    if (tid < 128) {
        float s = 0.f;
#pragma unroll 4
        for (int k = 0; k < KP; ++k)
            s += h[((size_t)hsl[k] * BN + b) * 128 + tid];
        hb[tid] = s * (1.f / 32.f);
    } else {
        int d = tid - 128;
        float s = 0.f;
#pragma unroll 4
        for (int k = 0; k < KP; ++k)
            s += c[((size_t)csl[k] * BN + b) * 128 + d];
        cb[d] = s * (1.f / 32.f);
    }
    __syncthreads();

    // phase 2: hc_proj[e] = hbar@W1[0:128] + cbar@W1[128:256] + b1
    {
        int e = tid & 127, half = tid >> 7;
        const float* Wb  = W1 + half * 128 * 128;
        const float* hcl = half ? cb : hb;
        float acc = 0.f;
#pragma unroll 8
        for (int d = 0; d < 128; ++d)
            acc = fmaf(hcl[d], Wb[d * 128 + e], acc);
        if (half) red[e] = acc;
        __syncthreads();
        if (!half) hcp[e] = acc + red[e] + b1[e];
    }
    __syncthreads();

    // phase 3: scores a[tq] = sum_e tanh(hcp[e]+encp[b,tq,e]) * W2[e] + b2
    {
        int w = tid >> 6, lane = tid & 63;
        for (int tt = 0; tt < 8; ++tt) {
            int tq = w * 8 + tt;
            float v = 0.f;
#pragma unroll
            for (int hh = 0; hh < 2; ++hh) {
                int e = lane + 64 * hh;
                v += tanhf(hcp[e] + encp[(b * TN + tq) * 128 + e]) * W2[e];
            }
#pragma unroll
            for (int off = 32; off; off >>= 1) v += __shfl_xor(v, off, 64);
            if (lane == 0) aa[tq] = v + b2v[0];
        }
    }
    __syncthreads();

    // phase 4: softmax over T (max-subtracted, like jax.nn.softmax)
    if (tid < 32) {
        float m = -1e30f;
        for (int i = 0; i < 32; ++i) m = fmaxf(m, aa[i]);
        float s = 0.f;
        for (int i = 0; i < 32; ++i) s += expf(aa[i] - m);
        beta[tid] = expf(aa[tid] - m) / s;
    }
    __syncthreads();

    // context + y_tilde
    if (tid < 128) {
        float acc = 0.f;
#pragma unroll 4
        for (int tq = 0; tq < 32; ++tq)
            acc = fmaf(beta[tq], enc[(b * TN + tq) * 128 + tid], acc);
        ctxg[b * 128 + tid] = acc;
        red[tid] = acc * fcW[tid];
    }
    __syncthreads();
    if (tid < 64) red[tid] += red[tid + 64];
    __syncthreads();
    if (tid < 64) {
        float v = red[tid];
#pragma unroll
        for (int off = 32; off; off >>= 1) v += __shfl_xor(v, off, 64);
        if (tid == 0) {
            float yv = v + yprev[b * TN + t] * fcW[128] + fcb[0];
            yts = yv;
            ytg[b] = yv;
        }
    }
    __syncthreads();

    // phase 6: var[j] = yt*varW[0,j] + hbar@varW[1:,j] + varb; softplus
    if (tid < 128) {
        int j = tid;
        float v = fmaf(yts, varW[j], varb[j]);
#pragma unroll 8
        for (int d = 0; d < 128; ++d)
            v = fmaf(hb[d], varW[(1 + d) * 128 + j], v);
        float sp = fmaxf(v, 0.f) + log1pf(expf(-fabsf(v)));
        vspg[b * 128 + j] = sp;
    }
}

// ---------------- LSTM step v2: barrier-free K-loop, Whh-reorg streamed from L2 ----------------
// 512 thr = 8 warps; warp w: rows (w&3)*8..+8 of block's 32, d0-half (w>>2).
// lane owns d0 = (w>>2)*64 + c0, 4 gates, 8 rows: acc[8][4]. Grid 256 (1 blk/CU, 8 waves/CU).
__global__ __launch_bounds__(512)
void k_lstm(const float* __restrict__ h, const float* __restrict__ c,
            const int* __restrict__ hsrc, const int* __restrict__ csrc,
            const float* __restrict__ Wre, const float* __restrict__ wihre,
            const float* __restrict__ bre,
            const float* __restrict__ yt, const float* __restrict__ vsp,
            const float* __restrict__ eps,
            const float* __restrict__ fdW, const float* __restrict__ pdW,
            float* __restrict__ h2, float* __restrict__ c2,
            float* __restrict__ proj, float* __restrict__ qv, int t) {
    __shared__ float hT[32 * 128];   // 16 KB
    __shared__ int hsl[32], csl[32];
    __shared__ float pp[32][2], qq[32][2];
    int tid  = threadIdx.x;
    int row0 = blockIdx.x * 32;
    int b0   = row0 & 255;
    int w = tid >> 6, c0 = tid & 63;
    int wr = w & 3, dh = w >> 2;
    int d0 = dh * 64 + c0;

    if (tid < 32) hsl[tid] = hsrc[row0 + tid];
    else if (tid < 64) csl[tid - 32] = csrc[row0 + tid - 32];
    __syncthreads();

    // stage gathered h tile (32 rows x 128), 2 float4 per thread
#pragma unroll
    for (int i = 0; i < 2; ++i) {
        int f4 = tid + 512 * i;
        int lr = f4 >> 5, off = f4 & 31;
        ((float4*)hT)[f4] =
            ((const float4*)h)[((size_t)hsl[lr] * BN + b0 + lr) * 32 + off];
    }
    __syncthreads();

    // init acc with yt*Wih + (bih+bhh), same fp order as before
    float4 wih4 = ((const float4*)wihre)[d0];
    float4 b4   = ((const float4*)bre)[d0];
    const float* wihp = (const float*)&wih4;
    const float* bp   = (const float*)&b4;
    float acc[8][4];
#pragma unroll
    for (int r = 0; r < 8; ++r) {
        float ytv = yt[b0 + wr * 8 + r];
#pragma unroll
        for (int g = 0; g < 4; ++g)
            acc[r][g] = fmaf(ytv, wihp[g], bp[g]);
    }

    // barrier-free K-loop: wv from L2 (coalesced dwordx4), hv from LDS (b128 broadcast)
    const float4* wp   = (const float4*)Wre + d0;
    const float*  hrow = hT + (wr * 8) * 128;
#pragma unroll 2
    for (int dq = 0; dq < 32; ++dq) {
        float4 wv[4];
#pragma unroll
        for (int j = 0; j < 4; ++j) wv[j] = wp[(dq * 4 + j) * 128];
        float4 hv[8];
#pragma unroll
        for (int r = 0; r < 8; ++r)
            hv[r] = *(const float4*)&hrow[r * 128 + dq * 4];
#pragma unroll
        for (int j = 0; j < 4; ++j) {
#pragma unroll
            for (int r = 0; r < 8; ++r) {
                float hvj = ((const float*)&hv[r])[j];
#pragma unroll
                for (int g = 0; g < 4; ++g)
                    acc[r][g] = fmaf(hvj, ((const float*)&wv[j])[g], acc[r][g]);
            }
        }
    }

    // epilogue: gates, reparam, stores, fused proj/pdf partial dots
    float fdv = fdW[d0], pdv = pdW[d0];
#pragma unroll
    for (int r = 0; r < 8; ++r) {
        int lr  = wr * 8 + r;
        int row = row0 + lr;
        int bb  = b0 + lr;
        float gi = acc[r][0], gf = acc[r][1], gg = acc[r][2], go = acc[r][3];
        float si = 1.f / (1.f + expf(-gi));
        float sf = 1.f / (1.f + expf(-gf));
        float so = 1.f / (1.f + expf(-go));
        float tg = tanhf(gg);
        float cold = c[((size_t)csl[lr] * BN + bb) * 128 + d0];
        float cn = sf * cold + si * tg;
        float hn = so * tanhf(cn);
        hn = fmaf(eps[((size_t)t * ROWS + row) * 128 + d0], vsp[bb * 128 + d0], hn);
        c2[(size_t)row * 128 + d0] = cn;
        h2[(size_t)row * 128 + d0] = hn;
        float p = hn * fdv, q = hn * pdv;
#pragma unroll
        for (int off = 32; off; off >>= 1) {
            p += __shfl_xor(p, off, 64);
            q += __shfl_xor(q, off, 64);
        }
        if (c0 == 0) { pp[lr][dh] = p; qq[lr][dh] = q; }
    }
    __syncthreads();
    if (tid < 32) proj[row0 + tid] = pp[tid][0] + pp[tid][1];
    else if (tid < 64) qv[row0 + tid - 32] = qq[tid - 32][0] + qq[tid - 32][1];
}

// ---------------- fused sort + weights (torch view(-1,K) bug) + resample ----------------
// one block per 32-batch chunk m; 1024 threads = 32 b_loc x 32 j
__global__ __launch_bounds__(1024)
void k_resample(const float* __restrict__ proj, const float* __restrict__ qv,
                const float* __restrict__ ytg, const float* __restrict__ pdW,
                const float* __restrict__ pdb, const float* __restrict__ gum,
                int* __restrict__ hsrc, int* __restrict__ csrc, int t) {
    __shared__ float pr[32][33];
    __shared__ int   ord[32][32];
    __shared__ float eps_s[32][33];  // [sorted s][b_loc]
    __shared__ float Sv[32];
    __shared__ float lw[32][33];     // [b_loc][sorted s]
    int tid = threadIdx.x;
    int bl = tid >> 5, j = tid & 31;
    int b = blockIdx.x * 32 + bl;

    pr[bl][j] = proj[j * BN + b];
    __syncthreads();

    // stable ascending argsort via rank
    {
        float pj = pr[bl][j];
        int r = 0;
#pragma unroll 8
        for (int l = 0; l < 32; ++l) {
            float pl = pr[bl][l];
            r += (pl < pj) || (pl == pj && l < j);
        }
        ord[bl][r] = j;
    }
    __syncthreads();

    // logpdf of sorted particle s=j ; exp
    {
        int jo = ord[bl][j];
        float lp = qv[jo * BN + b] + ytg[b] * pdW[128] + pdb[0];
        eps_s[j][bl] = expf(lp);
    }
    __syncthreads();

    // chunk sums S[s] (the replicated view(-1,K) normalization groups)
    if (tid < 32) {
        float s = 0.f;
#pragma unroll 8
        for (int l = 0; l < 32; ++l) s += eps_s[tid][l];
        Sv[tid] = s;
    }
    __syncthreads();

    lw[bl][j] = logf(eps_s[j][bl] / Sv[j] + 1e-30f);
    __syncthreads();

    // gumbel-max resample: knew = j ; first-occurrence argmax
    {
        const float* gb = gum + (((size_t)t * BN + b) * KP + j) * KP;
        float best = -1e38f;
        int bi = 0;
#pragma unroll 8
        for (int l = 0; l < 32; ++l) {
            float v = lw[bl][l] + gb[l];
            if (v > best) { best = v; bi = l; }
        }
        hsrc[j * BN + b] = ord[bl][bi];  // h2 sorted-gather composed -> original index
        csrc[j * BN + b] = bi;           // unsorted c2 gathered with sorted-space idx (ref bug)
    }
}

// ---------------- final outputs ----------------
__global__ void k_final(const float* __restrict__ h, const int* __restrict__ hsrc,
                        const float* __restrict__ ctx,
                        const float* __restrict__ fdW, const float* __restrict__ fdb,
                        const float* __restrict__ feW, const float* __restrict__ feb,
                        float* __restrict__ out) {
    int wid  = (blockIdx.x * 256 + threadIdx.x) >> 6;  // b
    int lane = threadIdx.x & 63;
    if (wid >= BN) return;
    float acc = 0.f;
#pragma unroll
    for (int hh = 0; hh < 2; ++hh) {
        int d = lane + 64 * hh;
        float s = 0.f;
#pragma unroll 4
        for (int k = 0; k < KP; ++k) {
            int hs = hsrc[k * BN + wid];
            s += h[((size_t)hs * BN + wid) * 128 + d];
        }
        acc = fmaf(s * (1.f / 32.f), fdW[d], acc);
        acc = fmaf(ctx[wid * 128 + d], feW[d], acc);
    }
#pragma unroll
    for (int off = 32; off; off >>= 1) acc += __shfl_xor(acc, off, 64);
    if (lane == 0) out[wid] = acc + fdb[0] + feb[0];
}

extern "C" void kernel_launch(void* const* d_in, const int* in_sizes, int n_in,
                              void* d_out, int out_size, void* d_ws, size_t ws_size,
                              hipStream_t stream) {
    const float* enc   = (const float*)d_in[0];
    const float* yprev = (const float*)d_in[1];
    const float* eps   = (const float*)d_in[2];
    const float* gum   = (const float*)d_in[3];
    const float* aW1   = (const float*)d_in[4];
    const float* ab1   = (const float*)d_in[5];
    const float* aW2   = (const float*)d_in[6];
    const float* ab2   = (const float*)d_in[7];
    const float* Wih   = (const float*)d_in[8];
    const float* Whh   = (const float*)d_in[9];
    const float* bih   = (const float*)d_in[10];
    const float* bhh   = (const float*)d_in[11];
    const float* fcW   = (const float*)d_in[12];
    const float* fcb   = (const float*)d_in[13];
    const float* fdW   = (const float*)d_in[14];
    const float* fdb   = (const float*)d_in[15];
    const float* feW   = (const float*)d_in[16];
    const float* feb   = (const float*)d_in[17];
    const float* varW  = (const float*)d_in[18];
    const float* varb  = (const float*)d_in[19];
    const float* pdW   = (const float*)d_in[20];
    const float* pdb   = (const float*)d_in[21];
    float* out = (float*)d_out;

    float* ws    = (float*)d_ws;
    float* encp  = ws;                        // 1,048,576
    float* h2A   = ws + 1048576;              // h2A,c2A contiguous for zero-init
    float* c2A   = ws + 2097152;
    float* h2B   = ws + 3145728;
    float* c2B   = ws + 4194304;
    float* ctx   = ws + 5242880;              // 32,768
    float* ytg   = ws + 5275648;              // 256
    float* vsp   = ws + 5275904;              // 32,768
    float* proj  = ws + 5308672;              // 8,192
    float* qv    = ws + 5316864;              // 8,192
    int*   hsrc  = (int*)(ws + 5325056);      // 8,192
    int*   csrc  = (int*)(ws + 5333248);      // 8,192
    float* Wre   = ws + 5341440;              // 65,536
    float* wihre = ws + 5406976;              // 512
    float* bre   = ws + 5407488;              // 512

    k_init<<<(2097152 + 255) / 256, 256, 0, stream>>>(h2A, hsrc, csrc);
    k_encproj<<<BN * TN, 128, 0, stream>>>(enc, aW1, encp);
    k_wre<<<64, 256, 0, stream>>>(Whh, Wih, bih, bhh, Wre, wihre, bre);

    float* hc = h2A; float* cc = c2A; float* hn = h2B; float* cn = c2B;
    for (int t = 0; t < TN; ++t) {
        k_attn<<<BN, 256, 0, stream>>>(hc, cc, hsrc, csrc, encp, enc, aW1, ab1, aW2, ab2,
                                       fcW, fcb, varW, varb, yprev, ctx, ytg, vsp, t);
        k_lstm<<<ROWS / 32, 512, 0, stream>>>(hc, cc, hsrc, csrc, Wre, wihre, bre,
                                              ytg, vsp, eps, fdW, pdW, hn, cn, proj, qv, t);
        k_resample<<<BN / 32, 1024, 0, stream>>>(proj, qv, ytg, pdW, pdb, gum,
                                                 hsrc, csrc, t);
        float* th = hc; hc = hn; hn = th;
        float* tc = cc; cc = cn; cn = tc;
    }
    k_final<<<64, 256, 0, stream>>>(hc, hsrc, ctx, fdW, fdb, feW, feb, out);
}